// Round 3
// baseline (6225.480 us; speedup 1.0000x reference)
//
#include <hip/hip_runtime.h>

// R3: XCD-local communication with runtime-verified placement + LLC fallback.
// 8 groups x 32 blocks x 256 thr (4 waves). Group == XCD when placement allows
// (verified via HW_REG_XCC_ID roster); then h/flag exchange rides the XCD's own
// L2 (plain write-through stores + sc0 polls, ~5x lower latency than LLC).
// Block owns 16 h-cols (64 gate-rows, 132KB LDS weights). No h-LDS staging:
// h A-frags are direct global loads at fresh t-indexed addresses (never stale).
// One barrier/step. Fallback (any roster count != 32): agent-scope everywhere.

#define T_STEPS 1024
#define BATCH   64
#define DIM     512
#define HID     512
#define KDIM    1024
#define NBLOCKS 256
#define TPB     256
#define NXCD    8
#define GSIZE   32   // blocks per group
#define GROWS   8    // batch rows per group

typedef __bf16 bf16_t;
typedef __bf16 bf16x8 __attribute__((ext_vector_type(8)));
typedef float  f32x4  __attribute__((ext_vector_type(4)));

// ---- workspace ----
#define WS_CTL_U32   272                       // flags[256] + roster[8] + gctr etc.
#define WS_WB_OFF    4096
#define WB_BYTES     ((size_t)32 * 64 * KDIM * 2)        // 4 MB packed weights
#define WS_HBUF_OFF  (WS_WB_OFF + WB_BYTES)
#define HBUF_BYTES   ((size_t)(T_STEPS + 1) * BATCH * HID * 2)
#define WS_REQUIRED  (WS_HBUF_OFF + HBUF_BYTES)          // ~71 MB

// ---- LDS: weights only ----
#define LROW_W 1032                       // +8 bf16 pad: b128 frag reads conflict-free
#define SMEM_W_BYTES (64 * LROW_W * 2)    // 132096
#define SMEM_BYTES   (SMEM_W_BYTES + 32)  // + comm[]

__device__ __forceinline__ unsigned pk2(float lo, float hi) {
  unsigned a = (unsigned)__builtin_bit_cast(unsigned short, (bf16_t)lo);
  unsigned b = (unsigned)__builtin_bit_cast(unsigned short, (bf16_t)hi);
  return (b << 16) | a;
}

__global__ void prep_kernel(const float* __restrict__ Wf, const float* __restrict__ Wi,
                            const float* __restrict__ Wg, const float* __restrict__ Wo,
                            unsigned* __restrict__ ctl, unsigned* __restrict__ Wb,
                            unsigned* __restrict__ hbuf0) {
  unsigned i = blockIdx.x * 256 + threadIdx.x;
  if (i < WS_CTL_U32) ctl[i] = 0u;            // flags + roster + gctr
  if (i < BATCH * HID / 2) hbuf0[i] = 0u;     // h_{-1} = 0
  if (i < 32u * 64u * 512u) {                 // pack weights (bf16 pairs)
    int slot = (int)(i >> 15);
    int rem = (int)(i & 32767);
    int row = rem >> 9, k2 = rem & 511;
    int w = row >> 4, cc = row & 15, gg = cc & 3, hl = cc >> 2;
    int h = slot * 16 + w * 4 + hl;
    const float* W = (gg == 0) ? Wf : (gg == 1) ? Wi : (gg == 2) ? Wg : Wo;
    float f0 = W[(size_t)h * KDIM + 2 * (size_t)k2];
    float f1 = W[(size_t)h * KDIM + 2 * (size_t)k2 + 1];
    Wb[i] = pk2(f0, f1);
  }
}

__global__ __launch_bounds__(TPB, 1) void lstm_kernel(
    const float* __restrict__ X,
    const float* __restrict__ bf_, const float* __restrict__ bi_,
    const float* __restrict__ bg_, const float* __restrict__ bo_,
    const float* __restrict__ qs_, const float* __restrict__ qb_,
    float* __restrict__ out,
    unsigned* __restrict__ flags, unsigned* __restrict__ roster,
    unsigned* __restrict__ gctr,
    const bf16_t* __restrict__ Wb, bf16_t* __restrict__ hbuf) {

  extern __shared__ char smem[];
  bf16_t* Wsl = (bf16_t*)smem;
  int* comm = (int*)(smem + SMEM_W_BYTES);
#define WSL(r, k) Wsl[(r) * LROW_W + (k)]

  const int tid = threadIdx.x;
  const int wv = tid >> 6, l = tid & 63;
  const int c = l & 15, rg = l >> 4, kq = rg * 8;
  const int gate = c & 3, hl = c >> 2;

  // ---- roster: verify 32 blocks per XCD; else fall back to LLC scope ----
  if (tid == 0) {
    unsigned xcc;
    asm volatile("s_getreg_b32 %0, hwreg(HW_REG_XCC_ID)" : "=s"(xcc));
    xcc &= 7u;
    unsigned tk = __hip_atomic_fetch_add(&roster[xcc], 1u, __ATOMIC_RELAXED,
                                         __HIP_MEMORY_SCOPE_AGENT);
    __hip_atomic_fetch_add(gctr, 1u, __ATOMIC_ACQ_REL, __HIP_MEMORY_SCOPE_AGENT);
    int cap = 0;
    while (__hip_atomic_load(gctr, __ATOMIC_ACQUIRE, __HIP_MEMORY_SCOPE_AGENT) <
           (unsigned)NBLOCKS)
      if (++cap > (1 << 24)) break;
    unsigned ok = 1;
    for (int x = 0; x < NXCD; x++)
      ok &= (__hip_atomic_load(&roster[x], __ATOMIC_RELAXED,
                               __HIP_MEMORY_SCOPE_AGENT) == (unsigned)GSIZE);
    comm[0] = (int)xcc; comm[1] = (int)tk; comm[2] = (int)ok;
  }
  __syncthreads();
  const int xcdm = comm[2];
  const int g    = xcdm ? comm[0] : ((int)blockIdx.x >> 5);
  const int slot = xcdm ? comm[1] : ((int)blockIdx.x & 31);
  const int bo   = g * GROWS;
  const int hcol = slot * 16 + wv * 4 + hl;
  const int myrow = bo + c;   // valid only under c<8 guards

  // ---- stage weight slice (slot-dependent, post-roster) ----
  {
    const uint4* src = (const uint4*)(Wb + (size_t)slot * 64 * KDIM);
#pragma unroll
    for (int ii = 0; ii < 32; ii++) {
      int idx = ii * TPB + tid;
      int sr = idx >> 7, k8 = idx & 127;
      *(uint4*)&WSL(sr, k8 * 8) = src[idx];
    }
  }
  const float* bsrc = (gate == 0) ? bf_ : (gate == 1) ? bi_ : (gate == 2) ? bg_ : bo_;
  const float bias = bsrc[hcol];
  const float qs = qs_[hcol], qb = qb_[hcol];
  float cst[4] = {0.f, 0.f, 0.f, 0.f};
  bf16x8 xf[16], hfr[16];
  {
    bf16x8 z;
#pragma unroll
    for (int i = 0; i < 8; i++) z[i] = (bf16_t)0.f;
#pragma unroll
    for (int i = 0; i < 16; i++) { xf[i] = z; hfr[i] = z; }
  }
  __syncthreads();

  unsigned* hb32 = (unsigned*)hbuf;
  const unsigned* fl = flags + g * GSIZE;
  unsigned* myflag = flags + g * GSIZE + slot;

  auto load_x = [&](int sidx) {
    if (c < 8) {
      const float* xs = X + ((size_t)sidx * BATCH + myrow) * DIM + kq;
#pragma unroll
      for (int kt = 0; kt < 16; kt++) {
        float4 a4 = *(const float4*)(xs + kt * 32);
        float4 b4 = *(const float4*)(xs + kt * 32 + 4);
        bf16x8 v;
        v[0] = (bf16_t)a4.x; v[1] = (bf16_t)a4.y; v[2] = (bf16_t)a4.z; v[3] = (bf16_t)a4.w;
        v[4] = (bf16_t)b4.x; v[5] = (bf16_t)b4.y; v[6] = (bf16_t)b4.z; v[7] = (bf16_t)b4.w;
        xf[kt] = v;
      }
    }
  };
  load_x(0);

  for (int s = 0; s < T_STEPS; s++) {
    // 1) x-half MFMAs (xf prefetched last step) — runs while peers finish
    f32x4 accA1 = {bias, bias, bias, bias}, accA2 = {0.f, 0.f, 0.f, 0.f};
#pragma unroll
    for (int kt = 0; kt < 8; kt++) {
      bf16x8 b = *(const bf16x8*)&WSL(wv * 16 + c, kq + kt * 32);
      accA1 = __builtin_amdgcn_mfma_f32_16x16x32_bf16(xf[kt], b, accA1, 0, 0, 0);
    }
#pragma unroll
    for (int kt = 8; kt < 16; kt++) {
      bf16x8 b = *(const bf16x8*)&WSL(wv * 16 + c, kq + kt * 32);
      accA2 = __builtin_amdgcn_mfma_f32_16x16x32_bf16(xf[kt], b, accA2, 0, 0, 0);
    }
    // 2) x-prefetch for s+1 — latency hides under the poll window
    load_x((s + 1 < T_STEPS) ? s + 1 : s);
    // 3) poll group flags (L2 in XCD mode, LLC in fallback)
    {
      const unsigned* fp = fl + (l & 31);
      int cap = 0;
      while (true) {
        unsigned v;
        if (xcdm)
          asm volatile("global_load_dword %0, %1, off sc0\n\ts_waitcnt vmcnt(0)"
                       : "=v"(v) : "v"(fp) : "memory");
        else
          asm volatile("global_load_dword %0, %1, off sc0 sc1\n\ts_waitcnt vmcnt(0)"
                       : "=v"(v) : "v"(fp) : "memory");
        if (__all((int)(v >= (unsigned)s))) break;
        if (++cap > (1 << 18)) break;  // wrong-answer beats hang
      }
    }
    // 4) h A-frags: direct global loads, fresh t-indexed addresses
    if (c < 8) {
      const bf16_t* hrow = hbuf + ((size_t)s * BATCH + myrow) * HID + kq;
#pragma unroll
      for (int kt = 0; kt < 16; kt++) hfr[kt] = *(const bf16x8*)(hrow + kt * 32);
    }
    // 5) h-half MFMAs (2 chains for ILP)
    f32x4 acc1 = {0.f, 0.f, 0.f, 0.f}, acc2 = {0.f, 0.f, 0.f, 0.f};
#pragma unroll
    for (int kt = 0; kt < 8; kt++) {
      bf16x8 b = *(const bf16x8*)&WSL(wv * 16 + c, 512 + kq + kt * 32);
      acc1 = __builtin_amdgcn_mfma_f32_16x16x32_bf16(hfr[kt], b, acc1, 0, 0, 0);
    }
#pragma unroll
    for (int kt = 8; kt < 16; kt++) {
      bf16x8 b = *(const bf16x8*)&WSL(wv * 16 + c, 512 + kq + kt * 32);
      acc2 = __builtin_amdgcn_mfma_f32_16x16x32_bf16(hfr[kt], b, acc2, 0, 0, 0);
    }
    // 6) epilogue: gates fp32, quad-lane exchange, cell update
    float hq[4];
#pragma unroll
    for (int q = 0; q < 4; q++) {
      float z = accA1[q] + accA2[q] + acc1[q] + acc2[q];
      float sg = 1.f / (1.f + __expf(-z));
      float th = 1.f - 2.f / (1.f + __expf(2.f * z));
      float a0 = (gate == 2) ? th : sg;
      float act = 1.f - 2.f / (1.f + __expf(2.f * (a0 * qs + qb)));
      float x1 = __shfl_xor(act, 1), x2 = __shfl_xor(act, 2), x3 = __shfl_xor(act, 3);
      float vf = (gate == 0) ? act : (gate == 1) ? x1 : (gate == 2) ? x2 : x3;
      float vi = (gate == 0) ? x1 : (gate == 1) ? act : (gate == 2) ? x3 : x2;
      float vg = (gate == 0) ? x2 : (gate == 1) ? x3 : (gate == 2) ? act : x1;
      float vo = (gate == 0) ? x3 : (gate == 1) ? x2 : (gate == 2) ? x1 : act;
      float cn = vf * cst[q] + vi * vg;
      cst[q] = cn;
      hq[q] = vo * (1.f - 2.f / (1.f + __expf(2.f * cn)));
    }
    // 7) publish h_s (gather 4 cols/wave into lane c==0 via shfl, 2 u32 stores)
#pragma unroll
    for (int q = 0; q < 4; q++) {
      float v4 = __shfl_xor(hq[q], 4);
      unsigned a = pk2(hq[q], v4);         // cols (hl, hl+1) on even-hl lanes
      unsigned b = __shfl_xor(a, 8);       // lane hl=0 receives cols (2,3)
      if (c == 0 && rg < 2) {
        int row = bo + rg * 4 + q;
        size_t idx = ((size_t)(s + 1) * BATCH + row) * (HID / 2) + slot * 8 + wv * 2;
        if (xcdm) {
          hb32[idx] = a; hb32[idx + 1] = b;          // write-through L1 -> local L2
        } else {
          __hip_atomic_store(&hb32[idx], a, __ATOMIC_RELAXED, __HIP_MEMORY_SCOPE_AGENT);
          __hip_atomic_store(&hb32[idx + 1], b, __ATOMIC_RELAXED, __HIP_MEMORY_SCOPE_AGENT);
        }
      }
    }
    // out stores (drained by the same vmcnt below)
    if (gate == 0 && rg < 2) {
      size_t ob = ((size_t)s * BATCH + bo + rg * 4) * HID + hcol;
      out[ob] = hq[0]; out[ob + HID] = hq[1];
      out[ob + 2 * HID] = hq[2]; out[ob + 3 * HID] = hq[3];
      if (s == T_STEPS - 1) {
        size_t hb = (size_t)T_STEPS * BATCH * HID + (size_t)(bo + rg * 4) * HID + hcol;
        size_t cb = hb + (size_t)BATCH * HID;
        out[hb] = hq[0]; out[hb + HID] = hq[1];
        out[hb + 2 * HID] = hq[2]; out[hb + 3 * HID] = hq[3];
        out[cb] = cst[0]; out[cb + HID] = cst[1];
        out[cb + 2 * HID] = cst[2]; out[cb + 3 * HID] = cst[3];
      }
    }
    // 8) drain stores, barrier, flag
    asm volatile("s_waitcnt vmcnt(0)" ::: "memory");
    __builtin_amdgcn_s_barrier();
    asm volatile("" ::: "memory");
    if (tid == 0) {
      unsigned fv = (unsigned)(s + 1);
      if (xcdm)
        asm volatile("global_store_dword %0, %1, off sc0" :: "v"(myflag), "v"(fv) : "memory");
      else
        __hip_atomic_store(myflag, fv, __ATOMIC_RELAXED, __HIP_MEMORY_SCOPE_AGENT);
    }
  }
#undef WSL
}

extern "C" void kernel_launch(void* const* d_in, const int* in_sizes, int n_in,
                              void* d_out, int out_size, void* d_ws, size_t ws_size,
                              hipStream_t stream) {
  const float* X  = (const float*)d_in[0];
  const float* Wf = (const float*)d_in[1];
  const float* bf = (const float*)d_in[2];
  const float* Wi = (const float*)d_in[3];
  const float* bi = (const float*)d_in[4];
  const float* Wg = (const float*)d_in[5];
  const float* bg = (const float*)d_in[6];
  const float* Wo = (const float*)d_in[7];
  const float* bo = (const float*)d_in[8];
  const float* qs = (const float*)d_in[9];
  const float* qb = (const float*)d_in[10];
  float* out = (float*)d_out;

  if (ws_size < WS_REQUIRED) return;  // fail loudly via absmax rather than corrupt

  char* ws = (char*)d_ws;
  unsigned* ctl    = (unsigned*)ws;
  unsigned* flags  = ctl;             // [0,256)
  unsigned* roster = ctl + 256;       // [256,264)
  unsigned* gctr   = ctl + 264;
  bf16_t* Wb   = (bf16_t*)(ws + WS_WB_OFF);
  bf16_t* hbuf = (bf16_t*)(ws + WS_HBUF_OFF);

  hipLaunchKernelGGL(prep_kernel, dim3(4096), dim3(256), 0, stream,
                     Wf, Wi, Wg, Wo, ctl, (unsigned*)Wb, (unsigned*)hbuf);

  (void)hipFuncSetAttribute((const void*)lstm_kernel,
                            hipFuncAttributeMaxDynamicSharedMemorySize, SMEM_BYTES);

  const bf16_t* Wbc = Wb;
  void* args[] = {(void*)&X, (void*)&bf, (void*)&bi, (void*)&bg, (void*)&bo,
                  (void*)&qs, (void*)&qb, (void*)&out, (void*)&flags,
                  (void*)&roster, (void*)&gctr, (void*)&Wbc, (void*)&hbuf};
  hipLaunchCooperativeKernel((void*)lstm_kernel, dim3(NBLOCKS), dim3(TPB),
                             args, SMEM_BYTES, stream);
}